// Round 4
// baseline (441.611 us; speedup 1.0000x reference)
//
#include <hip/hip_runtime.h>

// Problem constants (fixed by setup_inputs)
#define TB 16
#define NHEADS 16
#define HD 32
#define WS 8
#define SS 4
#define PPB 8   // problems per block: all 8 window-columns for fixed (b, wh, head)

typedef __attribute__((ext_vector_type(8))) __bf16 bf16x8;
typedef __attribute__((ext_vector_type(4))) float f32x4;

// LDS layout (bytes), one (window,head) problem at a time per 4-wave block:
//   [0,      5120)  Qs bf16 [64][40]  stride 80   -- overlaid by P after QK^T
//   [5120,  10240)  Ks bf16 [64][40]  stride 80   -- overlaid by P after QK^T
//   [0,      9216)  P  bf16 [64][72]  stride 144  (overlays Qs+Ks)
//   [10240, 14848)  Vt bf16 [32][72]  stride 144  (V transposed: [chan][token])
#define OFF_Q 0
#define OFF_K 5120
#define OFF_P 0
#define OFF_V 10240

__global__ __launch_bounds__(256, 5)
void swin_attn_mfma(const float* __restrict__ q,
                    const float* __restrict__ k,
                    const float* __restrict__ v,
                    const float* __restrict__ bias_table,
                    float* __restrict__ out)
{
    __shared__ __align__(16) char smem[14848];
    char* sQ = smem + OFF_Q;
    char* sK = smem + OFF_K;
    char* sP = smem + OFF_P;
    char* sV = smem + OFF_V;

    const int beta = blockIdx.x;            // 0..2047
    const int head = beta & (NHEADS - 1);
    const int wh   = (beta >> 4) & 7;
    const int b    = beta >> 7;

    const int tid  = threadIdx.x;           // 0..255
    const int wave = tid >> 6;              // 0..3  (tile row band mt)
    const int lane = tid & 63;
    const int quad = lane >> 4, lm = lane & 15;
    const int ih = lane >> 3, iw = lane & 7;    // lane = token it stages
    const int gh = (wh * WS + ih + SS) & 63;    // fixed across the problem loop

    // ---- persistent bias fragment (gathered once; head fixed per block) ----
    const int ihh  = 2 * wave + (quad >> 1);   // i>>3, constant per lane
    const int iww0 = 4 * (quad & 1);           // (i&7) - r
    const int jw   = lm & 7;                   // j&7
    f32x4 bias[4];
    #pragma unroll
    for (int nt = 0; nt < 4; ++nt) {
        const int jh = 2 * nt + (lm >> 3);
        #pragma unroll
        for (int r = 0; r < 4; ++r)
            bias[nt][r] = bias_table[((ihh - jh + 7) * 15 + (iww0 + r - jw + 7)) * NHEADS + head];
    }
    const bool eh = (wh == 7);

    // ---- staging source for this wave: wave0=Q, wave1=K, wave2/3=V halves ----
    const float* base = (wave == 0) ? q : (wave == 1) ? k : v;
    const int t0 = (wave == 3) ? 4 : 0;     // float4 offset within the row
    const size_t rowpre = ((size_t)(b * 64 + gh)) * 64;   // (+gw)*512 + head*HD later

    float4 R[8];   // staging buffer; loads for problem it+1 fly during compute of it

    // prologue: issue loads for it = 0
    {
        const int gw = (iw + SS) & 63;
        const float4* src = (const float4*)(base + (rowpre + gw) * 512 + head * HD) + t0;
        R[0] = src[0]; R[1] = src[1]; R[2] = src[2]; R[3] = src[3];
        if (wave < 2) { R[4] = src[4]; R[5] = src[5]; R[6] = src[6]; R[7] = src[7]; }
    }

    for (int it = 0; it < PPB; ++it) {
        __syncthreads();   // all LDS reads of the previous problem complete

        // ---- stage R -> LDS (f32 -> bf16; Q scaled) ----
        if (wave == 0) {
            const float scale = 0.17677669529663687f;  // 32^-0.5
            #pragma unroll
            for (int t = 0; t < 4; ++t) {
                float4 a = R[2 * t], c = R[2 * t + 1];
                bf16x8 w;
                w[0] = (__bf16)(a.x * scale); w[1] = (__bf16)(a.y * scale);
                w[2] = (__bf16)(a.z * scale); w[3] = (__bf16)(a.w * scale);
                w[4] = (__bf16)(c.x * scale); w[5] = (__bf16)(c.y * scale);
                w[6] = (__bf16)(c.z * scale); w[7] = (__bf16)(c.w * scale);
                *(bf16x8*)(sQ + lane * 80 + 16 * t) = w;
            }
        } else if (wave == 1) {
            #pragma unroll
            for (int t = 0; t < 4; ++t) {
                float4 a = R[2 * t], c = R[2 * t + 1];
                bf16x8 w;
                w[0] = (__bf16)a.x; w[1] = (__bf16)a.y;
                w[2] = (__bf16)a.z; w[3] = (__bf16)a.w;
                w[4] = (__bf16)c.x; w[5] = (__bf16)c.y;
                w[6] = (__bf16)c.z; w[7] = (__bf16)c.w;
                *(bf16x8*)(sK + lane * 80 + 16 * t) = w;
            }
        } else {
            #pragma unroll
            for (int t = 0; t < 4; ++t) {
                float4 x = R[t];
                const int ch = 4 * (t0 + t);
                *(__bf16*)(sV + (ch + 0) * 144 + lane * 2) = (__bf16)x.x;
                *(__bf16*)(sV + (ch + 1) * 144 + lane * 2) = (__bf16)x.y;
                *(__bf16*)(sV + (ch + 2) * 144 + lane * 2) = (__bf16)x.z;
                *(__bf16*)(sV + (ch + 3) * 144 + lane * 2) = (__bf16)x.w;
            }
        }

        // ---- prefetch next problem: in flight across this problem's compute ----
        if (it + 1 < PPB) {
            const int gw = ((it + 1) * WS + iw + SS) & 63;
            const float4* src = (const float4*)(base + (rowpre + gw) * 512 + head * HD) + t0;
            R[0] = src[0]; R[1] = src[1]; R[2] = src[2]; R[3] = src[3];
            if (wave < 2) { R[4] = src[4]; R[5] = src[5]; R[6] = src[6]; R[7] = src[7]; }
        }
        __syncthreads();   // staging visible

        // ---- QK^T: wave w computes tiles (mt=w, nt=0..3) ----
        bf16x8 qa = *(const bf16x8*)(sQ + (16 * wave + lm) * 80 + quad * 16);
        bf16x8 kb[4];
        #pragma unroll
        for (int nt = 0; nt < 4; ++nt)
            kb[nt] = *(const bf16x8*)(sK + (16 * nt + lm) * 80 + quad * 16);

        f32x4 S[4];
        #pragma unroll
        for (int nt = 0; nt < 4; ++nt) {
            f32x4 z = {0.f, 0.f, 0.f, 0.f};
            S[nt] = __builtin_amdgcn_mfma_f32_16x16x32_bf16(qa, kb[nt], z, 0, 0, 0);
        }
        // lane holds S[i][j]: i = 16*wave + 4*quad + r, j = 16*nt + lm

        // ---- softmax: bias + mask + exp in-register; row sums deferred ----
        const bool ew = (it == PPB - 1);   // ww == 7
        float part[4] = {0.f, 0.f, 0.f, 0.f};
        #pragma unroll
        for (int nt = 0; nt < 4; ++nt) {
            const int jh = 2 * nt + (lm >> 3);
            const bool okh = !eh || ((ihh < 4) == (jh < 4));
            #pragma unroll
            for (int r = 0; r < 4; ++r) {
                const int iww = iww0 + r;
                float s = S[nt][r] + bias[nt][r];
                bool ok = okh && (!ew || ((iww < 4) == (jw < 4)));
                float e = ok ? __expf(s) : 0.f;   // masked: exp(s-100) ~ 0
                S[nt][r] = e;
                part[r] += e;
            }
        }
        __syncthreads();   // all waves' Q/K fragment reads done before P overwrites

        // ---- write unnormalized E (bf16) over Q/K; shfl reduce overlaps ----
        #pragma unroll
        for (int nt = 0; nt < 4; ++nt)
            #pragma unroll
            for (int r = 0; r < 4; ++r)
                *(__bf16*)(sP + (16 * wave + 4 * quad + r) * 144 + (16 * nt + lm) * 2)
                    = (__bf16)S[nt][r];
        #pragma unroll
        for (int m = 1; m <= 8; m <<= 1)
            #pragma unroll
            for (int r = 0; r < 4; ++r)
                part[r] += __shfl_xor(part[r], m, 64);
        float rl[4];
        #pragma unroll
        for (int r = 0; r < 4; ++r)
            rl[r] = 1.f / part[r];
        __syncthreads();   // P visible

        // ---- PV: wave w computes tiles (mt=w, nt=0..1) ----
        bf16x8 pa0 = *(const bf16x8*)(sP + (16 * wave + lm) * 144 + quad * 16);
        bf16x8 pa1 = *(const bf16x8*)(sP + (16 * wave + lm) * 144 + 64 + quad * 16);
        bf16x8 vb[2][2];
        #pragma unroll
        for (int nt = 0; nt < 2; ++nt)
            #pragma unroll
            for (int ks = 0; ks < 2; ++ks)
                vb[nt][ks] = *(const bf16x8*)(sV + (16 * nt + lm) * 144 + ks * 64 + quad * 16);

        f32x4 O[2];
        #pragma unroll
        for (int nt = 0; nt < 2; ++nt) {
            f32x4 z = {0.f, 0.f, 0.f, 0.f};
            z = __builtin_amdgcn_mfma_f32_16x16x32_bf16(pa0, vb[nt][0], z, 0, 0, 0);
            O[nt] = __builtin_amdgcn_mfma_f32_16x16x32_bf16(pa1, vb[nt][1], z, 0, 0, 0);
        }

        // ---- store O * (1/l) ----
        #pragma unroll
        for (int r = 0; r < 4; ++r) {
            const int i = 16 * wave + 4 * quad + r;
            const int ghh = (wh * WS + (i >> 3) + SS) & 63;
            const int gww = (it * WS + (i & 7) + SS) & 63;
            float* rp = out + (((size_t)b * 64 + ghh) * 64 + gww) * 512 + (size_t)head * HD + lm;
            rp[0]  = O[0][r] * rl[r];
            rp[16] = O[1][r] * rl[r];
        }
    }
}

extern "C" void kernel_launch(void* const* d_in, const int* in_sizes, int n_in,
                              void* d_out, int out_size, void* d_ws, size_t ws_size,
                              hipStream_t stream) {
    const float* q  = (const float*)d_in[0];
    const float* k  = (const float*)d_in[1];
    const float* v  = (const float*)d_in[2];
    const float* bt = (const float*)d_in[3];
    float* out = (float*)d_out;

    dim3 grid(TB * 64 * NHEADS / PPB);   // 2048 blocks, each loops over 8 problems
    dim3 block(256);
    swin_attn_mfma<<<grid, block, 0, stream>>>(q, k, v, bt, out);
}

// Round 5
// 395.893 us; speedup vs baseline: 1.1155x; 1.1155x over previous
//
#include <hip/hip_runtime.h>

// Problem constants (fixed by setup_inputs)
#define TB 16
#define NHEADS 16
#define HD 32
#define WS 8
#define SS 4

typedef __attribute__((ext_vector_type(8))) __bf16 bf16x8;
typedef __attribute__((ext_vector_type(4))) __bf16 bf16x4;
typedef __attribute__((ext_vector_type(4))) float f32x4;

// LDS layout (bytes), one block = one window x 4 consecutive heads:
//   [0,      20480)  Q4 bf16 [4][64][40]  head stride 5120, token stride 80
//   [20480,  40960)  K4 bf16 [4][64][40]
//   [40960,  59392)  V4 bf16 [4][32][72]  head stride 4608, chan stride 144 (V^T)
//   [59392,  68608)  P  bf16 [64][72]     token stride 144 (recycled per head)
//   [68608,  72208)  B  f32  [4][225]
#define OFF_Q 0
#define OFF_K 20480
#define OFF_V 40960
#define OFF_P 59392
#define OFF_B 68608

__global__ __launch_bounds__(256, 2)
void swin_attn_mfma(const float* __restrict__ q,
                    const float* __restrict__ k,
                    const float* __restrict__ v,
                    const float* __restrict__ bias_table,
                    float* __restrict__ out)
{
    __shared__ __align__(16) char smem[72208];
    float* sB = (float*)(smem + OFF_B);
    char* sP = smem + OFF_P;

    const int blk = blockIdx.x;            // 0..4095
    const int hg  = blk & 3;               // head group: heads hg*4 .. hg*4+3
    const int win = (blk >> 2) & 63;
    const int b   = blk >> 8;
    const int wh  = win >> 3;
    const int ww  = win & 7;

    const int tid  = threadIdx.x;          // 0..255
    const int wave = tid >> 6;             // 0..3 (tile row band mt)
    const int lane = tid & 63;
    const int quad = lane >> 4, lm = lane & 15;

    // ---- staging map: 32 consecutive lanes read one token's 512B 4-head slice ----
    const int c4 = tid & 31;               // float4 index within the 512B slice
    const int tb = tid >> 5;               // iw of the staged token (0..7)
    const int hs = c4 >> 3;                // head-local this thread stages
    const int cw = c4 & 7;                 // float4 within the head's 128B slice

    // ---- stage bias for the 4 heads (re-gathered per block; L2-hot) ----
    if (tid < 225) {
        #pragma unroll
        for (int hl = 0; hl < 4; ++hl)
            sB[hl * 225 + tid] = bias_table[tid * NHEADS + hg * 4 + hl];
    }

    // ---- stage Q,K,V for 4 heads: 24 coalesced float4 loads per thread ----
    {
        const int gw = (ww * WS + tb + SS) & 63;
        float4 RQ[8], RK[8], RV[8];
        #pragma unroll
        for (int it = 0; it < 8; ++it) {
            const int gh = (wh * WS + it + SS) & 63;
            const size_t f4 = (((size_t)(b * 64 + gh) * 64 + gw) * 128) + hg * 32 + c4;
            RQ[it] = ((const float4*)q)[f4];
            RK[it] = ((const float4*)k)[f4];
            RV[it] = ((const float4*)v)[f4];
        }
        const float scale = 0.17677669529663687f;  // 32^-0.5
        #pragma unroll
        for (int it = 0; it < 8; ++it) {
            const int t = it * 8 + tb;     // token index (ih = it, iw = tb)
            float4 a = RQ[it];
            bf16x4 wq;
            wq[0] = (__bf16)(a.x * scale); wq[1] = (__bf16)(a.y * scale);
            wq[2] = (__bf16)(a.z * scale); wq[3] = (__bf16)(a.w * scale);
            *(bf16x4*)(smem + OFF_Q + hs * 5120 + t * 80 + cw * 8) = wq;
            float4 c = RK[it];
            bf16x4 wk;
            wk[0] = (__bf16)c.x; wk[1] = (__bf16)c.y;
            wk[2] = (__bf16)c.z; wk[3] = (__bf16)c.w;
            *(bf16x4*)(smem + OFF_K + hs * 5120 + t * 80 + cw * 8) = wk;
            float4 d = RV[it];
            char* vdst = smem + OFF_V + hs * 4608 + t * 2;
            *(__bf16*)(vdst + (cw * 4 + 0) * 144) = (__bf16)d.x;
            *(__bf16*)(vdst + (cw * 4 + 1) * 144) = (__bf16)d.y;
            *(__bf16*)(vdst + (cw * 4 + 2) * 144) = (__bf16)d.z;
            *(__bf16*)(vdst + (cw * 4 + 3) * 144) = (__bf16)d.w;
        }
    }
    __syncthreads();

    // ---- per-head compute: proven r1 pipeline, P in its own region ----
    const bool eh = (wh == 7), ew = (ww == 7);
    const int ihh  = 2 * wave + (quad >> 1);   // i>>3, constant per lane
    const int iww0 = 4 * (quad & 1);           // (i&7) - r
    const int jw   = lm & 7;                   // j&7

    #pragma unroll
    for (int hl = 0; hl < 4; ++hl) {
        const char* sQh = smem + OFF_Q + hl * 5120;
        const char* sKh = smem + OFF_K + hl * 5120;
        const char* sVh = smem + OFF_V + hl * 4608;
        const float* sBh = sB + hl * 225;

        // QK^T: wave w computes tiles (mt=w, nt=0..3)
        bf16x8 qa = *(const bf16x8*)(sQh + (16 * wave + lm) * 80 + quad * 16);
        bf16x8 kb[4];
        #pragma unroll
        for (int nt = 0; nt < 4; ++nt)
            kb[nt] = *(const bf16x8*)(sKh + (16 * nt + lm) * 80 + quad * 16);

        f32x4 S[4];
        #pragma unroll
        for (int nt = 0; nt < 4; ++nt) {
            f32x4 z = {0.f, 0.f, 0.f, 0.f};
            S[nt] = __builtin_amdgcn_mfma_f32_16x16x32_bf16(qa, kb[nt], z, 0, 0, 0);
        }
        // lane holds S[i][j]: i = 16*wave + 4*quad + r, j = 16*nt + lm

        // softmax: bias + mask + exp in-register; row sums deferred
        float part[4] = {0.f, 0.f, 0.f, 0.f};
        #pragma unroll
        for (int nt = 0; nt < 4; ++nt) {
            const int jh = 2 * nt + (lm >> 3);
            const bool okh = !eh || ((ihh < 4) == (jh < 4));
            #pragma unroll
            for (int r = 0; r < 4; ++r) {
                const int iww = iww0 + r;
                float s = S[nt][r] + sBh[(ihh - jh + 7) * 15 + (iww + 7 - jw)];
                bool ok = okh && (!ew || ((iww < 4) == (jw < 4)));
                float e = ok ? __expf(s) : 0.f;   // masked: exp(s-100) ~ 0
                S[nt][r] = e;
                part[r] += e;
            }
        }

        // write unnormalized E (bf16); shfl row-sum reduce overlaps LDS writes
        #pragma unroll
        for (int nt = 0; nt < 4; ++nt)
            #pragma unroll
            for (int r = 0; r < 4; ++r)
                *(__bf16*)(sP + (16 * wave + 4 * quad + r) * 144 + (16 * nt + lm) * 2)
                    = (__bf16)S[nt][r];
        #pragma unroll
        for (int m = 1; m <= 8; m <<= 1)
            #pragma unroll
            for (int r = 0; r < 4; ++r)
                part[r] += __shfl_xor(part[r], m, 64);
        float rl[4];
        #pragma unroll
        for (int r = 0; r < 4; ++r)
            rl[r] = 1.f / part[r];
        __syncthreads();   // P visible

        // PV: wave w computes tiles (mt=w, nt=0..1)
        bf16x8 pa0 = *(const bf16x8*)(sP + (16 * wave + lm) * 144 + quad * 16);
        bf16x8 pa1 = *(const bf16x8*)(sP + (16 * wave + lm) * 144 + 64 + quad * 16);
        bf16x8 vb[2][2];
        #pragma unroll
        for (int nt = 0; nt < 2; ++nt)
            #pragma unroll
            for (int ks = 0; ks < 2; ++ks)
                vb[nt][ks] = *(const bf16x8*)(sVh + (16 * nt + lm) * 144 + ks * 64 + quad * 16);

        f32x4 O[2];
        #pragma unroll
        for (int nt = 0; nt < 2; ++nt) {
            f32x4 z = {0.f, 0.f, 0.f, 0.f};
            z = __builtin_amdgcn_mfma_f32_16x16x32_bf16(pa0, vb[nt][0], z, 0, 0, 0);
            O[nt] = __builtin_amdgcn_mfma_f32_16x16x32_bf16(pa1, vb[nt][1], z, 0, 0, 0);
        }

        // store O * (1/l)
        const int head = hg * 4 + hl;
        #pragma unroll
        for (int r = 0; r < 4; ++r) {
            const int i = 16 * wave + 4 * quad + r;
            const int ghh = (wh * WS + (i >> 3) + SS) & 63;
            const int gww = (ww * WS + (i & 7) + SS) & 63;
            float* rp = out + (((size_t)b * 64 + ghh) * 64 + gww) * 512 + (size_t)head * HD + lm;
            rp[0]  = O[0][r] * rl[r];
            rp[16] = O[1][r] * rl[r];
        }
        __syncthreads();   // P region free for next head's writes
    }
}

extern "C" void kernel_launch(void* const* d_in, const int* in_sizes, int n_in,
                              void* d_out, int out_size, void* d_ws, size_t ws_size,
                              hipStream_t stream) {
    const float* q  = (const float*)d_in[0];
    const float* k  = (const float*)d_in[1];
    const float* v  = (const float*)d_in[2];
    const float* bt = (const float*)d_in[3];
    float* out = (float*)d_out;

    dim3 grid(TB * 64 * 4);   // 4096 blocks = (batch, window, head-group-of-4)
    dim3 block(256);
    swin_attn_mfma<<<grid, block, 0, stream>>>(q, k, v, bt, out);
}